// Round 4
// baseline (3595.494 us; speedup 1.0000x reference)
//
#include <hip/hip_runtime.h>

// GeneralConv_30820685316781 — full-f32 VALU correctness build (no MFMA, no bf16 intermediates)
#define N_ 40000
#define E_ 320000
#define D_ 128
#define H_ 4
#define T_ 3
#define R_ 5

typedef unsigned short u16;

__device__ __forceinline__ float bf2f(u16 h){ return __uint_as_float(((unsigned)h)<<16); }
__device__ __forceinline__ u16 f2bf(float f){
  unsigned u = __float_as_uint(f);
  u += 0x7fffu + ((u>>16)&1u);     // RNE
  return (u16)(u>>16);
}
__device__ __forceinline__ unsigned fmono(float f){
  unsigned u = __float_as_uint(f);
  return (u>>31) ? ~u : (u | 0x80000000u);
}
__device__ __forceinline__ float monof(unsigned u){
  return (u>>31) ? __uint_as_float(u & 0x7fffffffu) : __uint_as_float(~u);
}
// flag-driven input load: f32 storage or bf16 storage
__device__ __forceinline__ float ldx(const void* p, long i, int f32){
  return f32 ? ((const float*)p)[i] : bf2f(((const u16*)p)[i]);
}
__device__ __forceinline__ float wredsum(float v){
  #pragma unroll
  for (int m=32;m;m>>=1) v += __shfl_xor(v, m, 64);
  return v;
}

// wcf element offsets (f32 canonical weight buffer)
#define W_QW 0
#define W_KW 49152
#define W_VW 98304
#define W_AW 147456
#define W_QB 196608
#define W_KB 196992
#define W_VB 197376
#define W_AB 197760
#define W_PRI 198144
#define W_RATT 198164
#define W_RMSG 218644
#define W_WMK 239124
#define W_WAK 288276
#define W_WQ 337428
#define W_BQ 353812
#define W_WKL 353940
#define W_BKL 370324
#define W_SKIP 370452
#define W_LNG 370455
#define W_LNB 370839
#define W_TOT 371223

// ---- workspace layout (bytes). Peak 114,445,312 (~109 MiB). ----
#define OFF_FLAGS 0ul
#define OFF_WCF   256ul
#define OFF_NT32  1485312ul
#define OFF_EI32  1645312ul
#define OFF_ET32  4205312ul
#define OFF_QN    5485312ul     // qn (s2-s6) -> aggm2[0] (s8-s10) -> trans (s11-s12)
#define OFF_KN    25965312ul    // kn (s3-s6) -> aggm2[1] (s8-s10)
#define OFF_VN    46445312ul    // vn (s4-s8: aggk input)
#define OFF_QLIN  66925312ul    // qlin (s5-s10) -> hbuf in-place (gate: all reads before barrier+write)
#define OFF_AG2   87405312ul    // aggm2[2] (s8-s10)
#define OFF_LOG   107885312ul   // logits 5.12M | mxkey 0.64M | sumex 0.64M | deg 0.16M

// ---------------------------------------------------------------------------
// flags[0]=1 if float inputs stored f32; flags[1]=1 if int inputs stored i64
__global__ __launch_bounds__(256) void detect_kernel(
    const u16* __restrict__ xs, const int* __restrict__ nt, int* __restrict__ flags)
{
  __shared__ int sBig, sZero, sNz;
  int tid = threadIdx.x;
  if (tid==0){ sBig=0; sZero=0; sNz=0; }
  __syncthreads();
  int big=0, zc=0;
  for (int i=tid; i<1024; i+=256) {
    u16 v = xs[2*i];               // low half if f32, element 2i if bf16
    int e = (v>>7)&0xFF;
    big += (e >= 200);
    zc  += (v == 0);
  }
  int nz=0;
  for (int i=tid; i<1024; i+=256) nz += (nt[2*i+1] != 0);
  atomicAdd(&sBig, big); atomicAdd(&sZero, zc); atomicAdd(&sNz, nz);
  __syncthreads();
  if (tid==0) {
    flags[0] = (sBig > 64) || (sZero > 900);
    flags[1] = (sNz == 0);
  }
}

// canonicalize the 20 weight arrays into f32 wcf
struct FPtrs { const void* p[20]; };
__global__ __launch_bounds__(256) void convf_kernel(
    const int* __restrict__ flags, FPtrs ptrs, float* __restrict__ wcf)
{
  const int start[21] = {0,49152,98304,147456,196608,196992,197376,197760,198144,
    198164,218644,239124,288276,337428,353812,353940,370324,370452,370455,370839,371223};
  int i = blockIdx.x*256 + threadIdx.x;
  if (i >= W_TOT) return;
  int arr = 0;
  #pragma unroll
  for (int a=1; a<20; ++a) arr += (i >= start[a]);
  int local = i - start[arr];
  wcf[i] = ldx(ptrs.p[arr], local, flags[0]);
}

// index arrays -> int32
__global__ __launch_bounds__(256) void idxconv_kernel(
    const int* __restrict__ flags,
    const int* __restrict__ nt, const int* __restrict__ ei, const int* __restrict__ et,
    int* __restrict__ nt32, int* __restrict__ ei32, int* __restrict__ et32)
{
  int i = blockIdx.x*256 + threadIdx.x;
  if (i >= 1000000) return;
  int w = flags[1] ? 2 : 1;        // i64: take low word
  if (i < 40000)        nt32[i] = nt[(long)i*w];
  else if (i < 680000)  { int j=i-40000;  ei32[j] = ei[(long)j*w]; }
  else                  { int j=i-680000; et32[j] = et[(long)j*w]; }
}

__global__ __launch_bounds__(256) void init_kernel(
    unsigned* __restrict__ mxkey, float* __restrict__ sumex, int* __restrict__ deg)
{
  int i = blockIdx.x*256 + threadIdx.x;   // 625*256 = N*H
  mxkey[i] = fmono(-1e30f);
  sumex[i] = 0.f;
  if (i < N_) deg[i] = 0;
}

// ---------------------------------------------------------------------------
// VALU GEMM [rows,128]@[128,128] f32: block 256 = 2 rows x 128 cols.
// X via flag-load (xmode=1 forces f32 scratch input). Typed weight/bias select.
__global__ __launch_bounds__(256) void gemmv_kernel(
    const void* __restrict__ X, const int* __restrict__ flags, int xmode,
    const float* __restrict__ wcf, int woff, int boff,
    const int* __restrict__ rtype, float* __restrict__ out)
{
  int xf = xmode ? 1 : flags[0];
  int col = threadIdx.x & 127, rloc = threadIdx.x >> 7;
  int row = blockIdx.x*2 + rloc;
  int t = rtype ? rtype[row] : 0;
  const float* Wc = wcf + woff + t*16384;
  long xb = (long)row*128;
  float acc = 0.f;
  #pragma unroll 8
  for (int i=0;i<128;++i)
    acc += ldx(X, xb+i, xf) * Wc[i*128+col];
  if (boff >= 0) acc += wcf[boff + t*128 + col];
  out[xb + col] = acc;
}

// ---------------------------------------------------------------------------
// fused edge logits: logit[e,h] = (qn[t,h,:]·(rel_att[r,h]^T·kn[s,h,:]))·pri/sqrt(32)
__global__ __launch_bounds__(256) void elog_kernel(
    const float* __restrict__ qn, const float* __restrict__ kn, const float* __restrict__ wcf,
    const int* __restrict__ ei, const int* __restrict__ et,
    float* __restrict__ logits, unsigned* __restrict__ mxkey, int* __restrict__ deg)
{
  int gid = blockIdx.x*256 + threadIdx.x;   // E*H
  int e = gid >> 2, h = gid & 3;
  int s = ei[e], t = ei[E_+e], r = et[e];
  const float* kr = kn + (long)s*128 + h*32;
  const float* qr = qn + (long)t*128 + h*32;
  const float* ra = wcf + W_RATT + (r*H_+h)*1024;    // [d][m] 32x32
  float kreg[32];
  #pragma unroll
  for (int d=0;d<32;++d) kreg[d] = kr[d];
  float acc = 0.f;
  for (int m=0;m<32;++m){
    float kp = 0.f;
    #pragma unroll 8
    for (int d=0;d<32;++d) kp += kreg[d]*ra[d*32+m];
    acc += qr[m]*kp;
  }
  float lg = acc * wcf[W_PRI + r*H_+h] * 0.17677669529663687f;  // 1/sqrt(32)
  logits[gid] = lg;
  atomicMax(mxkey + t*H_+h, fmono(lg));
  if (h==0) atomicAdd(deg + t, 1);
}

// ex = exp(min(logit - mx[tgt],0)); segment-sum per (tgt,h)
__global__ __launch_bounds__(256) void eexp_kernel(
    const int* __restrict__ ei, float* __restrict__ logits,
    const unsigned* __restrict__ mxkey, float* __restrict__ sumex)
{
  int gid = blockIdx.x*256 + threadIdx.x;
  int e = gid >> 2, h = gid & 3;
  int t = ei[E_+e];
  float d = fminf(logits[gid] - monof(mxkey[t*H_+h]), 0.f);
  float ex = expf(d);
  logits[gid] = ex;
  atomicAdd(sumex + t*H_+h, ex);
}

// ---------------------------------------------------------------------------
// batched k: aggm2[k] = A_k @ WMk[k], with A_k[n,j] = deg(n)·att[n,h]·vp[n,j]^(k+1)
// (k=2 signed-cube-rooted), vp computed on the fly from vn[src[n]]·rel_msg.
// block 256 = 2 rows x 128 cols; A staged in LDS.
__global__ __launch_bounds__(256) void aggk_kernel(
    const float* __restrict__ vn, const float* __restrict__ wcf,
    const int* __restrict__ ei, const int* __restrict__ et,
    const float* __restrict__ ex, const float* __restrict__ sumex, const int* __restrict__ deg,
    float* __restrict__ out0, float* __restrict__ out1, float* __restrict__ out2)
{
  __shared__ float As[2][128];
  int k = blockIdx.y;
  int col = threadIdx.x & 127, rloc = threadIdx.x >> 7;
  int n = blockIdx.x*2 + rloc;          // node id == edge id (reference's faithful bug)
  int h = col >> 5, m = col & 31;
  int s = ei[n], t = ei[E_+n], r = et[n];
  const float* vr = vn + (long)s*128 + h*32;
  const float* rm = wcf + W_RMSG + (r*H_+h)*1024;    // [d][m]
  float vp = 0.f;
  #pragma unroll 8
  for (int d=0;d<32;++d) vp += vr[d]*rm[d*32+m];
  float att = ex[n*H_+h] / (sumex[t*H_+h] + 1e-16f);
  float sc  = (float)deg[n] * att;
  float a;
  if (k==0)      a = vp*sc;
  else if (k==1) a = vp*vp*sc;
  else { float a3 = vp*vp*vp*sc;
         a = (a3==0.f) ? 0.f : copysignf(cbrtf(fabsf(a3)+1e-18f), a3); }
  As[rloc][col] = a;
  __syncthreads();
  const float* Wk = wcf + W_WMK + k*16384;
  float acc = 0.f;
  #pragma unroll 8
  for (int i=0;i<128;++i) acc += As[rloc][i]*Wk[i*128+col];
  float* out = (k==0)?out0:(k==1)?out1:out2;
  out[(long)n*128 + col] = acc;
}

// ---------------------------------------------------------------------------
// fused gate: per node, for k: front=qlin@Wak[k], tail=aggm2[k]@Wkl+bkl,
// t_k=sigmoid(<front,tail>), res+=t_k·aggm2[k]; h=gelu_exact(res).
// hout may alias qlin (barrier before write; only row n touched by block n).
__global__ __launch_bounds__(128) void gate_kernel(
    const float* __restrict__ qlin, const float* __restrict__ wcf,
    const float* __restrict__ ag0, const float* __restrict__ ag1, const float* __restrict__ ag2,
    float* __restrict__ hout)
{
  __shared__ float rs[128];
  int j = threadIdx.x;
  int n = blockIdx.x;
  long xb = (long)n*128;
  const float* ags[3] = {ag0, ag1, ag2};
  float res = 0.f;
  for (int k=0;k<3;++k){
    const float* Wa = wcf + W_WAK + k*16384;
    float fr = 0.f;
    #pragma unroll 8
    for (int i=0;i<128;++i) fr += qlin[xb+i]*Wa[i*128+j];
    const float* ak = ags[k] + xb;
    float tl = wcf[W_BKL + j];
    #pragma unroll 8
    for (int i=0;i<128;++i) tl += ak[i]*wcf[W_WKL + i*128+j];
    rs[j] = fr*tl;
    __syncthreads();
    for (int sft=64; sft; sft>>=1){
      if (j < sft) rs[j] += rs[j+sft];
      __syncthreads();
    }
    float tot = rs[0];
    __syncthreads();
    float tk = 1.f/(1.f+expf(-tot));
    res += tk * ak[j];
  }
  __syncthreads();   // all qlin reads complete before aliased write
  float g = 0.5f*res*(1.f+erff(res*0.70710678118654752f));
  hout[xb + j] = g;
}

// skip-mix + per-type LayerNorm; dual-dtype store
__global__ __launch_bounds__(256) void lnf_kernel(
    const float* __restrict__ trans, const void* __restrict__ x, const int* __restrict__ flags,
    const int* __restrict__ nt, const float* __restrict__ wcf, void* __restrict__ outv)
{
  int wave = threadIdx.x >> 6, lane = threadIdx.x & 63;
  int n = blockIdx.x*4 + wave;
  int j = lane*2;
  int xf = flags[0];
  int t = nt[n];
  float alpha = 1.f/(1.f+expf(-wcf[W_SKIP+t]));
  long base = (long)n*128 + j;
  float y0 = alpha*trans[base]   + (1.f-alpha)*ldx(x, base,   xf);
  float y1 = alpha*trans[base+1] + (1.f-alpha)*ldx(x, base+1, xf);
  float mu = wredsum(y0+y1) * (1.f/128.f);
  float d0 = y0-mu, d1 = y1-mu;
  float var = wredsum(d0*d0+d1*d1) * (1.f/128.f);
  float inv = rsqrtf(var + 1e-5f);
  float o0 = d0*inv*wcf[W_LNG + t*128+j]   + wcf[W_LNB + t*128+j];
  float o1 = d1*inv*wcf[W_LNG + t*128+j+1] + wcf[W_LNB + t*128+j+1];
  if (xf) {
    ((float*)outv)[base]   = o0;
    ((float*)outv)[base+1] = o1;
  } else {
    unsigned o = (unsigned)f2bf(o0) | ((unsigned)f2bf(o1)<<16);
    *reinterpret_cast<unsigned*>(((u16*)outv)+base) = o;
  }
}

// ---------------------------------------------------------------------------
extern "C" void kernel_launch(void* const* d_in, const int* in_sizes, int n_in,
                              void* d_out, int out_size, void* d_ws, size_t ws_size,
                              hipStream_t stream) {
  char* w = (char*)d_ws;
  int*      flags = (int*)     (w + OFF_FLAGS);
  float*    wcf   = (float*)   (w + OFF_WCF);
  int*      nt32  = (int*)     (w + OFF_NT32);
  int*      ei32  = (int*)     (w + OFF_EI32);
  int*      et32  = (int*)     (w + OFF_ET32);
  float*    qn    = (float*)   (w + OFF_QN);
  float*    ag0   = (float*)   (w + OFF_QN);    // aggm2[0] overlays qn
  float*    trans = (float*)   (w + OFF_QN);    // trans overlays aggm2[0]
  float*    kn    = (float*)   (w + OFF_KN);
  float*    ag1   = (float*)   (w + OFF_KN);    // aggm2[1] overlays kn
  float*    vn    = (float*)   (w + OFF_VN);
  float*    qlin  = (float*)   (w + OFF_QLIN);
  float*    hbuf  = (float*)   (w + OFF_QLIN);  // in-place over qlin (row-local)
  float*    ag2   = (float*)   (w + OFF_AG2);
  float*    logits= (float*)   (w + OFF_LOG);
  unsigned* mxkey = (unsigned*)(w + OFF_LOG + 5120000);
  float*    sumex = (float*)   (w + OFF_LOG + 5760000);
  int*      deg   = (int*)     (w + OFF_LOG + 6400000);

  // s0: detect storage dtypes
  detect_kernel<<<1,256,0,stream>>>((const u16*)d_in[0], (const int*)d_in[1], flags);
  // s0.5: canonicalize weights (f32) and indices (i32)
  FPtrs fp;
  fp.p[0]=d_in[5];  fp.p[1]=d_in[7];  fp.p[2]=d_in[9];  fp.p[3]=d_in[11];
  fp.p[4]=d_in[6];  fp.p[5]=d_in[8];  fp.p[6]=d_in[10]; fp.p[7]=d_in[12];
  fp.p[8]=d_in[13]; fp.p[9]=d_in[14]; fp.p[10]=d_in[15];fp.p[11]=d_in[16];
  fp.p[12]=d_in[17];fp.p[13]=d_in[18];fp.p[14]=d_in[19];fp.p[15]=d_in[20];
  fp.p[16]=d_in[21];fp.p[17]=d_in[22];fp.p[18]=d_in[23];fp.p[19]=d_in[24];
  convf_kernel<<<1451,256,0,stream>>>(flags, fp, wcf);
  idxconv_kernel<<<3907,256,0,stream>>>(flags, (const int*)d_in[1],
                                        (const int*)d_in[2], (const int*)d_in[3],
                                        nt32, ei32, et32);

  // s2-s5: qn/kn/vn (typed) + qlin, straight from d_in[0]
  gemmv_kernel<<<20000,256,0,stream>>>(d_in[0],flags,0, wcf, W_QW, W_QB, nt32, qn);
  gemmv_kernel<<<20000,256,0,stream>>>(d_in[0],flags,0, wcf, W_KW, W_KB, nt32, kn);
  gemmv_kernel<<<20000,256,0,stream>>>(d_in[0],flags,0, wcf, W_VW, W_VB, nt32, vn);
  gemmv_kernel<<<20000,256,0,stream>>>(d_in[0],flags,0, wcf, W_WQ, W_BQ, nullptr, qlin);

  // s5.5: init softmax accumulators
  init_kernel<<<625,256,0,stream>>>(mxkey, sumex, deg);

  // s6-s7: fused edge logits (qt on the fly), then exp+segment-sum
  elog_kernel<<<5000,256,0,stream>>>(qn, kn, wcf, ei32, et32, logits, mxkey, deg);
  eexp_kernel<<<5000,256,0,stream>>>(ei32, logits, mxkey, sumex);

  // s8: aggm2[k] = (deg·att·vp^(k+1)) @ WMk[k]  (vp on the fly; k=2 rooted)
  aggk_kernel<<<dim3(20000,3),256,0,stream>>>(vn, wcf, ei32, et32, logits, sumex, deg,
                                              ag0, ag1, ag2);

  // s10: fused gate + gelu -> hbuf (in-place over qlin)
  gate_kernel<<<40000,128,0,stream>>>(qlin, wcf, ag0, ag1, ag2, hbuf);

  // s11: trans = typed(h, a_w, a_b)
  gemmv_kernel<<<20000,256,0,stream>>>(hbuf,flags,1, wcf, W_AW, W_AB, nt32, trans);

  // s12: skip-mix + per-type LayerNorm -> out
  lnf_kernel<<<10000,256,0,stream>>>(trans, d_in[0], flags, nt32, wcf, d_out);

  (void)in_sizes; (void)n_in; (void)out_size; (void)ws_size;
}

// Round 5
// 1954.538 us; speedup vs baseline: 1.8396x; 1.8396x over previous
//
#include <hip/hip_runtime.h>

// GeneralConv_30820685316781 — f32 VALU build, round 5: elog restructure + gate bilinear
#define N_ 40000
#define E_ 320000
#define D_ 128
#define H_ 4
#define T_ 3
#define R_ 5

typedef unsigned short u16;

__device__ __forceinline__ float bf2f(u16 h){ return __uint_as_float(((unsigned)h)<<16); }
__device__ __forceinline__ u16 f2bf(float f){
  unsigned u = __float_as_uint(f);
  u += 0x7fffu + ((u>>16)&1u);     // RNE
  return (u16)(u>>16);
}
__device__ __forceinline__ unsigned fmono(float f){
  unsigned u = __float_as_uint(f);
  return (u>>31) ? ~u : (u | 0x80000000u);
}
__device__ __forceinline__ float monof(unsigned u){
  return (u>>31) ? __uint_as_float(u & 0x7fffffffu) : __uint_as_float(~u);
}
__device__ __forceinline__ float ldx(const void* p, long i, int f32){
  return f32 ? ((const float*)p)[i] : bf2f(((const u16*)p)[i]);
}
__device__ __forceinline__ float wredsum(float v){
  #pragma unroll
  for (int m=32;m;m>>=1) v += __shfl_xor(v, m, 64);
  return v;
}

// wcf element offsets (f32 canonical weight buffer)
#define W_QW 0
#define W_KW 49152
#define W_VW 98304
#define W_AW 147456
#define W_QB 196608
#define W_KB 196992
#define W_VB 197376
#define W_AB 197760
#define W_PRI 198144
#define W_RATT 198164
#define W_RMSG 218644
#define W_WMK 239124
#define W_WAK 288276
#define W_WQ 337428
#define W_BQ 353812
#define W_WKL 353940
#define W_BKL 370324
#define W_SKIP 370452
#define W_LNG 370455
#define W_LNB 370839
#define W_TOT 371223

// ---- workspace layout (bytes). Peak 115,365,376 (~110 MiB). ----
#define OFF_FLAGS 0ul
#define OFF_WCF   256ul
#define OFF_RAT   1485312ul    // raT[r][h][m][d]  5*4*1024 f32
#define OFF_MT    1567232ul    // MT[k][i*128+col] = M_k[col,i], M_k = Wak_k @ Wkl^T
#define OFF_CK    1763840ul    // ck[k][col] = sum_j Wak_k[col,j]*bkl[j]
#define OFF_NT32  1765376ul
#define OFF_EI32  1925376ul
#define OFF_ET32  4485376ul
#define OFF_TVAL  5765376ul    // tval[n*4+k] sigmoid gates
#define OFF_LOG   6405376ul    // logits 5.12M | mxkey .64M | sumex .64M | deg .16M
#define OFF_QN    12965376ul   // qn -> ag0 -> trans
#define OFF_KN    33445376ul   // kn -> ag1
#define OFF_VN    53925376ul   // vn
#define OFF_QLIN  74405376ul   // qlin -> hbuf
#define OFF_QTR   94885376ul   // qtr (s6 loop) -> ag2

// ---------------------------------------------------------------------------
__global__ __launch_bounds__(256) void detect_kernel(
    const u16* __restrict__ xs, const int* __restrict__ nt, int* __restrict__ flags)
{
  __shared__ int sBig, sZero, sNz;
  int tid = threadIdx.x;
  if (tid==0){ sBig=0; sZero=0; sNz=0; }
  __syncthreads();
  int big=0, zc=0;
  for (int i=tid; i<1024; i+=256) {
    u16 v = xs[2*i];
    int e = (v>>7)&0xFF;
    big += (e >= 200);
    zc  += (v == 0);
  }
  int nz=0;
  for (int i=tid; i<1024; i+=256) nz += (nt[2*i+1] != 0);
  atomicAdd(&sBig, big); atomicAdd(&sZero, zc); atomicAdd(&sNz, nz);
  __syncthreads();
  if (tid==0) {
    flags[0] = (sBig > 64) || (sZero > 900);
    flags[1] = (sNz == 0);
  }
}

struct FPtrs { const void* p[20]; };
__global__ __launch_bounds__(256) void convf_kernel(
    const int* __restrict__ flags, FPtrs ptrs, float* __restrict__ wcf)
{
  const int start[21] = {0,49152,98304,147456,196608,196992,197376,197760,198144,
    198164,218644,239124,288276,337428,353812,353940,370324,370452,370455,370839,371223};
  int i = blockIdx.x*256 + threadIdx.x;
  if (i >= W_TOT) return;
  int arr = 0;
  #pragma unroll
  for (int a=1; a<20; ++a) arr += (i >= start[a]);
  int local = i - start[arr];
  wcf[i] = ldx(ptrs.p[arr], local, flags[0]);
}

__global__ __launch_bounds__(256) void idxconv_kernel(
    const int* __restrict__ flags,
    const int* __restrict__ nt, const int* __restrict__ ei, const int* __restrict__ et,
    int* __restrict__ nt32, int* __restrict__ ei32, int* __restrict__ et32)
{
  int i = blockIdx.x*256 + threadIdx.x;
  if (i >= 1000000) return;
  int w = flags[1] ? 2 : 1;
  if (i < 40000)        nt32[i] = nt[(long)i*w];
  else if (i < 680000)  { int j=i-40000;  ei32[j] = ei[(long)j*w]; }
  else                  { int j=i-680000; et32[j] = et[(long)j*w]; }
}

__global__ __launch_bounds__(256) void init_kernel(
    unsigned* __restrict__ mxkey, float* __restrict__ sumex, int* __restrict__ deg)
{
  int i = blockIdx.x*256 + threadIdx.x;   // 625*256 = N*H
  mxkey[i] = fmono(-1e30f);
  sumex[i] = 0.f;
  if (i < N_) deg[i] = 0;
}

// prepA: raT[r][h][m][d] = rel_att[r][h][d][m]   (coalesced d-lanes for qtr kernel)
__global__ __launch_bounds__(256) void prepA_kernel(
    const float* __restrict__ wcf, float* __restrict__ raT)
{
  int i = blockIdx.x*256 + threadIdx.x;   // 80 blocks: 20480 elems
  if (i >= 20480) return;
  int d = i & 31, m = (i>>5) & 31, rh = i >> 10;
  raT[i] = wcf[W_RATT + (rh*32 + d)*32 + m];
}

// prepB: MT[k][i*128+col] = sum_j Wak_k[col,j]*Wkl[i,j];  ck[k][col] = sum_j Wak_k[col,j]*bkl[j]
__global__ __launch_bounds__(128) void prepB_kernel(
    const float* __restrict__ wcf, float* __restrict__ MT, float* __restrict__ ck)
{
  int col = threadIdx.x, i = blockIdx.x, k = blockIdx.y;
  const float* wak = wcf + W_WAK + k*16384 + col*128;
  const float* wkl = wcf + W_WKL + i*128;
  float acc = 0.f, accC = 0.f;
  #pragma unroll 8
  for (int j=0;j<128;++j) {
    float a = wak[j];
    acc  += a * wkl[j];
    if (i==0) accC += a * wcf[W_BKL + j];
  }
  MT[k*16384 + i*128 + col] = acc;
  if (i==0) ck[k*128 + col] = accC;
}

// ---------------------------------------------------------------------------
// VALU GEMM [rows,128]@[128,128] f32: block 256 = 2 rows x 128 cols (round-4 proven)
__global__ __launch_bounds__(256) void gemmv_kernel(
    const void* __restrict__ X, const int* __restrict__ flags, int xmode,
    const float* __restrict__ wcf, int woff, int boff,
    const int* __restrict__ rtype, float* __restrict__ out)
{
  int xf = xmode ? 1 : flags[0];
  int col = threadIdx.x & 127, rloc = threadIdx.x >> 7;
  int row = blockIdx.x*2 + rloc;
  int t = rtype ? rtype[row] : 0;
  const float* Wc = wcf + woff + t*16384;
  long xb = (long)row*128;
  float acc = 0.f;
  #pragma unroll 8
  for (int i=0;i<128;++i)
    acc += ldx(X, xb+i, xf) * Wc[i*128+col];
  if (boff >= 0) acc += wcf[boff + t*128 + col];
  out[xb + col] = acc;
}

// qtr[n, h*32+d] = sum_m qn[n,h*32+m] * rel_att[r,h,d,m]  (via raT, coalesced)
__global__ __launch_bounds__(256) void qtr_kernel(
    const float* __restrict__ qn, const float* __restrict__ raT_r,
    float* __restrict__ qtr)
{
  int col = threadIdx.x & 127, rloc = threadIdx.x >> 7;
  int row = blockIdx.x*2 + rloc;
  int h = col >> 5, d = col & 31;
  const float* xr = qn + (long)row*128 + h*32;
  const float* rt = raT_r + h*1024;       // [m][d]
  float acc = 0.f;
  #pragma unroll 8
  for (int m=0;m<32;++m) acc += xr[m] * rt[m*32+d];
  qtr[(long)row*128 + col] = acc;
}

// per-relation edge pass: logit = dot32(kn[src,h], qtr[tgt,h]) * pri / sqrt(32)
__global__ __launch_bounds__(256) void epass_kernel(
    const float* __restrict__ kn, const float* __restrict__ qtr, const float* __restrict__ wcf,
    const int* __restrict__ ei, const int* __restrict__ et, int rsel,
    float* __restrict__ logits, unsigned* __restrict__ mxkey, int* __restrict__ deg)
{
  int gid = blockIdx.x*256 + threadIdx.x;   // E*H
  int e = gid >> 2, h = gid & 3;
  if (et[e] != rsel) return;
  int s = ei[e], t = ei[E_+e];
  const float4* ka = reinterpret_cast<const float4*>(kn + (long)s*128 + h*32);
  const float4* qa = reinterpret_cast<const float4*>(qtr + (long)t*128 + h*32);
  float acc = 0.f;
  #pragma unroll
  for (int i=0;i<8;++i) {
    float4 a = ka[i], b = qa[i];
    acc += a.x*b.x + a.y*b.y + a.z*b.z + a.w*b.w;
  }
  float lg = acc * wcf[W_PRI + rsel*H_+h] * 0.17677669529663687f;
  logits[gid] = lg;
  atomicMax(mxkey + t*H_+h, fmono(lg));
  if (h==0) atomicAdd(deg + t, 1);
}

__global__ __launch_bounds__(256) void eexp_kernel(
    const int* __restrict__ ei, float* __restrict__ logits,
    const unsigned* __restrict__ mxkey, float* __restrict__ sumex)
{
  int gid = blockIdx.x*256 + threadIdx.x;
  int e = gid >> 2, h = gid & 3;
  int t = ei[E_+e];
  float d = fminf(logits[gid] - monof(mxkey[t*H_+h]), 0.f);
  float ex = expf(d);
  logits[gid] = ex;
  atomicAdd(sumex + t*H_+h, ex);
}

// ---------------------------------------------------------------------------
// aggm2[k] = A_k @ WMk[k], A_k[n,j] = deg(n)·att[n,h]·vp[n,j]^(k+1) (k=2 cube-rooted)
__global__ __launch_bounds__(256) void aggk_kernel(
    const float* __restrict__ vn, const float* __restrict__ wcf,
    const int* __restrict__ ei, const int* __restrict__ et,
    const float* __restrict__ ex, const float* __restrict__ sumex, const int* __restrict__ deg,
    float* __restrict__ out0, float* __restrict__ out1, float* __restrict__ out2)
{
  __shared__ float As[2][128];
  int k = blockIdx.y;
  int col = threadIdx.x & 127, rloc = threadIdx.x >> 7;
  int n = blockIdx.x*2 + rloc;
  int h = col >> 5, m = col & 31;
  int s = ei[n], t = ei[E_+n], r = et[n];
  const float* vr = vn + (long)s*128 + h*32;
  const float* rm = wcf + W_RMSG + (r*H_+h)*1024;
  float vp = 0.f;
  #pragma unroll 8
  for (int d=0;d<32;++d) vp += vr[d]*rm[d*32+m];
  float att = ex[n*H_+h] / (sumex[t*H_+h] + 1e-16f);
  float sc  = (float)deg[n] * att;
  float a;
  if (k==0)      a = vp*sc;
  else if (k==1) a = vp*vp*sc;
  else { float a3 = vp*vp*vp*sc;
         a = (a3==0.f) ? 0.f : copysignf(cbrtf(fabsf(a3)+1e-18f), a3); }
  As[rloc][col] = a;
  __syncthreads();
  const float* Wk = wcf + W_WMK + k*16384;
  float acc = 0.f;
  #pragma unroll 8
  for (int i=0;i<128;++i) acc += As[rloc][i]*Wk[i*128+col];
  float* out = (k==0)?out0:(k==1)?out1:out2;
  out[(long)n*128 + col] = acc;
}

// ---------------------------------------------------------------------------
// gemmdot: t[n,k] = sigmoid( dot(qlin[n], ag_k[n]@MT_k + ck_k) )
// block 256 = 2 rows x 128 cols; fused dot + sigmoid epilogue
__global__ __launch_bounds__(256) void gemmdot_kernel(
    const float* __restrict__ ag0, const float* __restrict__ ag1, const float* __restrict__ ag2,
    const float* __restrict__ qlin, const float* __restrict__ MT, const float* __restrict__ ck,
    float* __restrict__ tval)
{
  __shared__ float wred[4];
  int k = blockIdx.y;
  int col = threadIdx.x & 127, rloc = threadIdx.x >> 7;
  int row = blockIdx.x*2 + rloc;
  const float* ag = (k==0)?ag0:(k==1)?ag1:ag2;
  const float* W = MT + k*16384;
  long xb = (long)row*128;
  float acc = 0.f;
  #pragma unroll 8
  for (int i=0;i<128;++i) acc += ag[xb+i]*W[i*128+col];
  acc += ck[k*128+col];
  float p = acc * qlin[xb+col];
  float v = wredsum(p);
  if ((threadIdx.x & 63) == 0) wred[threadIdx.x>>6] = v;
  __syncthreads();
  if (threadIdx.x == 0)   tval[(long)(blockIdx.x*2  )*4 + k] = 1.f/(1.f+expf(-(wred[0]+wred[1])));
  if (threadIdx.x == 128) tval[(long)(blockIdx.x*2+1)*4 + k] = 1.f/(1.f+expf(-(wred[2]+wred[3])));
}

// gatemix: res = sum_k t_k·ag_k; h = gelu_exact(res)
__global__ __launch_bounds__(256) void gatemix_kernel(
    const float* __restrict__ tval,
    const float* __restrict__ ag0, const float* __restrict__ ag1, const float* __restrict__ ag2,
    float* __restrict__ hout)
{
  long gid = (long)blockIdx.x*256 + threadIdx.x;   // N*128
  int n = (int)(gid >> 7);
  float res = tval[n*4+0]*ag0[gid] + tval[n*4+1]*ag1[gid] + tval[n*4+2]*ag2[gid];
  hout[gid] = 0.5f*res*(1.f+erff(res*0.70710678118654752f));
}

__global__ __launch_bounds__(256) void lnf_kernel(
    const float* __restrict__ trans, const void* __restrict__ x, const int* __restrict__ flags,
    const int* __restrict__ nt, const float* __restrict__ wcf, void* __restrict__ outv)
{
  int wave = threadIdx.x >> 6, lane = threadIdx.x & 63;
  int n = blockIdx.x*4 + wave;
  int j = lane*2;
  int xf = flags[0];
  int t = nt[n];
  float alpha = 1.f/(1.f+expf(-wcf[W_SKIP+t]));
  long base = (long)n*128 + j;
  float y0 = alpha*trans[base]   + (1.f-alpha)*ldx(x, base,   xf);
  float y1 = alpha*trans[base+1] + (1.f-alpha)*ldx(x, base+1, xf);
  float mu = wredsum(y0+y1) * (1.f/128.f);
  float d0 = y0-mu, d1 = y1-mu;
  float var = wredsum(d0*d0+d1*d1) * (1.f/128.f);
  float inv = rsqrtf(var + 1e-5f);
  float o0 = d0*inv*wcf[W_LNG + t*128+j]   + wcf[W_LNB + t*128+j];
  float o1 = d1*inv*wcf[W_LNG + t*128+j+1] + wcf[W_LNB + t*128+j+1];
  if (xf) {
    ((float*)outv)[base]   = o0;
    ((float*)outv)[base+1] = o1;
  } else {
    unsigned o = (unsigned)f2bf(o0) | ((unsigned)f2bf(o1)<<16);
    *reinterpret_cast<unsigned*>(((u16*)outv)+base) = o;
  }
}

// ---------------------------------------------------------------------------
extern "C" void kernel_launch(void* const* d_in, const int* in_sizes, int n_in,
                              void* d_out, int out_size, void* d_ws, size_t ws_size,
                              hipStream_t stream) {
  char* w = (char*)d_ws;
  int*      flags = (int*)     (w + OFF_FLAGS);
  float*    wcf   = (float*)   (w + OFF_WCF);
  float*    raT   = (float*)   (w + OFF_RAT);
  float*    MT    = (float*)   (w + OFF_MT);
  float*    ck    = (float*)   (w + OFF_CK);
  int*      nt32  = (int*)     (w + OFF_NT32);
  int*      ei32  = (int*)     (w + OFF_EI32);
  int*      et32  = (int*)     (w + OFF_ET32);
  float*    tval  = (float*)   (w + OFF_TVAL);
  float*    logits= (float*)   (w + OFF_LOG);
  unsigned* mxkey = (unsigned*)(w + OFF_LOG + 5120000);
  float*    sumex = (float*)   (w + OFF_LOG + 5760000);
  int*      deg   = (int*)     (w + OFF_LOG + 6400000);
  float*    qn    = (float*)   (w + OFF_QN);
  float*    ag0   = (float*)   (w + OFF_QN);
  float*    trans = (float*)   (w + OFF_QN);
  float*    kn    = (float*)   (w + OFF_KN);
  float*    ag1   = (float*)   (w + OFF_KN);
  float*    vn    = (float*)   (w + OFF_VN);
  float*    qlin  = (float*)   (w + OFF_QLIN);
  float*    hbuf  = (float*)   (w + OFF_QLIN);
  float*    qtr   = (float*)   (w + OFF_QTR);
  float*    ag2   = (float*)   (w + OFF_QTR);

  // s0: dtype detect + canonicalize
  detect_kernel<<<1,256,0,stream>>>((const u16*)d_in[0], (const int*)d_in[1], flags);
  FPtrs fp;
  fp.p[0]=d_in[5];  fp.p[1]=d_in[7];  fp.p[2]=d_in[9];  fp.p[3]=d_in[11];
  fp.p[4]=d_in[6];  fp.p[5]=d_in[8];  fp.p[6]=d_in[10]; fp.p[7]=d_in[12];
  fp.p[8]=d_in[13]; fp.p[9]=d_in[14]; fp.p[10]=d_in[15];fp.p[11]=d_in[16];
  fp.p[12]=d_in[17];fp.p[13]=d_in[18];fp.p[14]=d_in[19];fp.p[15]=d_in[20];
  fp.p[16]=d_in[21];fp.p[17]=d_in[22];fp.p[18]=d_in[23];fp.p[19]=d_in[24];
  convf_kernel<<<1451,256,0,stream>>>(flags, fp, wcf);
  idxconv_kernel<<<3907,256,0,stream>>>(flags, (const int*)d_in[1],
                                        (const int*)d_in[2], (const int*)d_in[3],
                                        nt32, ei32, et32);
  // s1: prep raT + MT/ck
  prepA_kernel<<<80,256,0,stream>>>(wcf, raT);
  prepB_kernel<<<dim3(128,3),128,0,stream>>>(wcf, MT, ck);

  // s2-s5: qn/kn/vn (typed) + qlin
  gemmv_kernel<<<20000,256,0,stream>>>(d_in[0],flags,0, wcf, W_QW, W_QB, nt32, qn);
  gemmv_kernel<<<20000,256,0,stream>>>(d_in[0],flags,0, wcf, W_KW, W_KB, nt32, kn);
  gemmv_kernel<<<20000,256,0,stream>>>(d_in[0],flags,0, wcf, W_VW, W_VB, nt32, vn);
  gemmv_kernel<<<20000,256,0,stream>>>(d_in[0],flags,0, wcf, W_WQ, W_BQ, nullptr, qlin);

  // s5.5: init softmax accumulators
  init_kernel<<<625,256,0,stream>>>(mxkey, sumex, deg);

  // s6: per-relation qtr + edge pass (qtr buffer reused across r)
  for (int r=0; r<R_; ++r) {
    qtr_kernel<<<20000,256,0,stream>>>(qn, raT + r*4096, qtr);
    epass_kernel<<<5000,256,0,stream>>>(kn, qtr, wcf, ei32, et32, r, logits, mxkey, deg);
  }
  // s7: exp + segment-sum
  eexp_kernel<<<5000,256,0,stream>>>(ei32, logits, mxkey, sumex);

  // s8: aggm2[k] (vp on the fly)
  aggk_kernel<<<dim3(20000,3),256,0,stream>>>(vn, wcf, ei32, et32, logits, sumex, deg,
                                              ag0, ag1, ag2);

  // s9: gate scalars via bilinear GEMM+dot
  gemmdot_kernel<<<dim3(20000,3),256,0,stream>>>(ag0, ag1, ag2, qlin, MT, ck, tval);

  // s10: mix + gelu -> hbuf (overlays qlin; qlin dead after gemmdot)
  gatemix_kernel<<<20000,256,0,stream>>>(tval, ag0, ag1, ag2, hbuf);

  // s11: trans = typed(h, a_w, a_b)
  gemmv_kernel<<<20000,256,0,stream>>>(hbuf,flags,1, wcf, W_AW, W_AB, nt32, trans);

  // s12: skip-mix + per-type LayerNorm -> out
  lnf_kernel<<<10000,256,0,stream>>>(trans, d_in[0], flags, nt32, wcf, d_out);

  (void)in_sizes; (void)n_in; (void)out_size; (void)ws_size;
}

// Round 6
// 1525.342 us; speedup vs baseline: 2.3572x; 1.2814x over previous
//
#include <hip/hip_runtime.h>

// GeneralConv_30820685316781 — f32 build, round 6: LDS-tiled register-blocked GEMM (gemmt)
#define N_ 40000
#define E_ 320000
#define D_ 128
#define H_ 4
#define T_ 3
#define R_ 5

typedef unsigned short u16;

__device__ __forceinline__ float bf2f(u16 h){ return __uint_as_float(((unsigned)h)<<16); }
__device__ __forceinline__ u16 f2bf(float f){
  unsigned u = __float_as_uint(f);
  u += 0x7fffu + ((u>>16)&1u);     // RNE
  return (u16)(u>>16);
}
__device__ __forceinline__ unsigned fmono(float f){
  unsigned u = __float_as_uint(f);
  return (u>>31) ? ~u : (u | 0x80000000u);
}
__device__ __forceinline__ float monof(unsigned u){
  return (u>>31) ? __uint_as_float(u & 0x7fffffffu) : __uint_as_float(~u);
}
__device__ __forceinline__ float ldx(const void* p, long i, int f32){
  return f32 ? ((const float*)p)[i] : bf2f(((const u16*)p)[i]);
}
__device__ __forceinline__ float wredsum(float v){
  #pragma unroll
  for (int m=32;m;m>>=1) v += __shfl_xor(v, m, 64);
  return v;
}

// wcf element offsets (f32 canonical weight buffer)
#define W_QW 0
#define W_KW 49152
#define W_VW 98304
#define W_AW 147456
#define W_QB 196608
#define W_KB 196992
#define W_VB 197376
#define W_AB 197760
#define W_PRI 198144
#define W_RATT 198164
#define W_RMSG 218644
#define W_WMK 239124
#define W_WAK 288276
#define W_WQ 337428
#define W_BQ 353812
#define W_WKL 353940
#define W_BKL 370324
#define W_SKIP 370452
#define W_LNG 370455
#define W_LNB 370839
#define W_TOT 371223

// ---- workspace layout (bytes). Peak 115,248,640 < round-5 proven 115,365,376. ----
#define OFF_FLAGS 0ul
#define OFF_WCF   512ul
#define OFF_NT32  1485824ul
#define OFF_EI32  1646080ul
#define OFF_ET32  4206592ul
#define OFF_PERM  5486592ul    // 40192 ints (type-sorted rows, 64-aligned groups, -1 pad)
#define OFF_PCNT  5647360ul    // cnt[0..3] | fill[4..7] | ofs[8..11]
#define OFF_TVAL  5647872ul    // raT (s1-s6, 80KB) then tval (s9-s10, 640000B)
#define OFF_LOG   6288384ul    // logits 5.12M | mxkey .64M | sumex .64M | deg .16M
                               // after aggk: MT (196608) + ck (1536) overlay logits
#define OFF_QN    12848640ul   // qn -> ag0 -> trans
#define OFF_KN    33328640ul   // kn -> ag1
#define OFF_VN    53808640ul   // vn
#define OFF_QLIN  74288640ul   // qlin -> hbuf
#define OFF_QTR   94768640ul   // qtr (s6) -> ag2

// ---------------------------------------------------------------------------
__global__ __launch_bounds__(256) void detect_kernel(
    const u16* __restrict__ xs, const int* __restrict__ nt, int* __restrict__ flags)
{
  __shared__ int sBig, sZero, sNz;
  int tid = threadIdx.x;
  if (tid==0){ sBig=0; sZero=0; sNz=0; }
  __syncthreads();
  int big=0, zc=0;
  for (int i=tid; i<1024; i+=256) {
    u16 v = xs[2*i];
    int e = (v>>7)&0xFF;
    big += (e >= 200);
    zc  += (v == 0);
  }
  int nz=0;
  for (int i=tid; i<1024; i+=256) nz += (nt[2*i+1] != 0);
  atomicAdd(&sBig, big); atomicAdd(&sZero, zc); atomicAdd(&sNz, nz);
  __syncthreads();
  if (tid==0) {
    flags[0] = (sBig > 64) || (sZero > 900);
    flags[1] = (sNz == 0);
  }
}

struct FPtrs { const void* p[20]; };
__global__ __launch_bounds__(256) void convf_kernel(
    const int* __restrict__ flags, FPtrs ptrs, float* __restrict__ wcf)
{
  const int start[21] = {0,49152,98304,147456,196608,196992,197376,197760,198144,
    198164,218644,239124,288276,337428,353812,353940,370324,370452,370455,370839,371223};
  int i = blockIdx.x*256 + threadIdx.x;
  if (i >= W_TOT) return;
  int arr = 0;
  #pragma unroll
  for (int a=1; a<20; ++a) arr += (i >= start[a]);
  int local = i - start[arr];
  wcf[i] = ldx(ptrs.p[arr], local, flags[0]);
}

__global__ __launch_bounds__(256) void idxconv_kernel(
    const int* __restrict__ flags,
    const int* __restrict__ nt, const int* __restrict__ ei, const int* __restrict__ et,
    int* __restrict__ nt32, int* __restrict__ ei32, int* __restrict__ et32)
{
  int i = blockIdx.x*256 + threadIdx.x;
  if (i >= 1000000) return;
  int w = flags[1] ? 2 : 1;
  if (i < 40000)        nt32[i] = nt[(long)i*w];
  else if (i < 680000)  { int j=i-40000;  ei32[j] = ei[(long)j*w]; }
  else                  { int j=i-680000; et32[j] = et[(long)j*w]; }
}

// ---- type-sorted permutation (64-aligned groups, -1 padding) ----
__global__ __launch_bounds__(256) void pinit_kernel(int* __restrict__ perm, int* __restrict__ pc){
  int i = blockIdx.x*256 + threadIdx.x;
  if (i < 40192) perm[i] = -1;
  if (i < 12) pc[i] = 0;
}
__global__ __launch_bounds__(256) void pcount_kernel(const int* __restrict__ nt, int* __restrict__ pc){
  int i = blockIdx.x*256 + threadIdx.x;
  if (i < N_) atomicAdd(&pc[nt[i]], 1);
}
__global__ void pofs_kernel(int* __restrict__ pc){
  if (threadIdx.x==0 && blockIdx.x==0) {
    pc[8] = 0;
    pc[9] = (pc[0]+63)&~63;
    pc[10] = pc[9] + ((pc[1]+63)&~63);
  }
}
__global__ __launch_bounds__(256) void pscat_kernel(const int* __restrict__ nt,
    int* __restrict__ pc, int* __restrict__ perm){
  int i = blockIdx.x*256 + threadIdx.x;
  if (i >= N_) return;
  int t = nt[i];
  int pos = pc[8+t] + atomicAdd(&pc[4+t], 1);
  perm[pos] = i;
}

__global__ __launch_bounds__(256) void init_kernel(
    unsigned* __restrict__ mxkey, float* __restrict__ sumex, int* __restrict__ deg)
{
  int i = blockIdx.x*256 + threadIdx.x;   // 625*256 = N*H
  mxkey[i] = fmono(-1e30f);
  sumex[i] = 0.f;
  if (i < N_) deg[i] = 0;
}

// prepA: raT[r][h][m][d] = rel_att[r][h][d][m]
__global__ __launch_bounds__(256) void prepA_kernel(
    const float* __restrict__ wcf, float* __restrict__ raT)
{
  int i = blockIdx.x*256 + threadIdx.x;
  if (i >= 20480) return;
  int d = i & 31, m = (i>>5) & 31, rh = i >> 10;
  raT[i] = wcf[W_RATT + (rh*32 + d)*32 + m];
}

// prepB: MT[k][i*128+col] = sum_j Wak_k[col,j]*Wkl[i,j];  ck[k][col] = sum_j Wak_k[col,j]*bkl[j]
__global__ __launch_bounds__(128) void prepB_kernel(
    const float* __restrict__ wcf, float* __restrict__ MT, float* __restrict__ ck)
{
  int col = threadIdx.x, i = blockIdx.x, k = blockIdx.y;
  const float* wak = wcf + W_WAK + k*16384 + col*128;
  const float* wkl = wcf + W_WKL + i*128;
  float acc = 0.f, accC = 0.f;
  #pragma unroll 8
  for (int j=0;j<128;++j) {
    float a = wak[j];
    acc  += a * wkl[j];
    if (i==0) accC += a * wcf[W_BKL + j];
  }
  MT[k*16384 + i*128 + col] = acc;
  if (i==0) ck[k*128 + col] = accC;
}

// ---------------------------------------------------------------------------
// gemmt: LDS-tiled f32 GEMM [64 rows x 128 cols per block], K=128 in 4 chunks.
// W = Wbase + y*ybstride + t_blk*16384 (t_blk uniform per block via type-sorted perm).
// dotmode: tval[row*4+y] = sigmoid( sum_col (acc+ck_y)[col] * qlin[row,col] )
struct P3 { const float* a[3]; };
__global__ __launch_bounds__(256) void gemmt_kernel(
    P3 xs, const int* __restrict__ flags, int xmode,
    const float* __restrict__ Wbase, int ybstride,
    const float* __restrict__ bias, int ybias,
    const int* __restrict__ perm, const int* __restrict__ nt,
    int dotmode, const float* __restrict__ qlin, const float* __restrict__ ck,
    float* __restrict__ out, long yostride)
{
  __shared__ float As[64*36];     // 64 rows x 32 k, stride 36 (pad)
  __shared__ float Ws[4096];      // 32 k x 128 cols, linear
  __shared__ int ridx[64];
  __shared__ int tblk_s;
  int tid = threadIdx.x;
  int y = blockIdx.y;
  int row0 = blockIdx.x*64;
  if (tid < 64) {
    int rr = row0 + tid;
    int rg = perm ? perm[rr] : (rr < N_ ? rr : -1);
    ridx[tid] = rg;
    if (tid==0) tblk_s = (perm && nt && rg>=0) ? nt[rg] : 0;
  }
  __syncthreads();
  if (ridx[0] < 0) return;        // fully padded block (uniform)
  int tblk = tblk_s;
  const float* Wg = Wbase + (long)y*ybstride + (long)tblk*16384;
  const void* X = (const void*)xs.a[y];
  int xf = xmode ? 1 : flags[0];

  int rg_ = tid >> 5;             // 8 row-groups of 8 rows
  int cg  = tid & 31;             // 32 col-groups of 4 cols
  float acc[8][4];
  #pragma unroll
  for (int r=0;r<8;++r){ acc[r][0]=0.f; acc[r][1]=0.f; acc[r][2]=0.f; acc[r][3]=0.f; }

  int sar = tid >> 2;             // staging: row 0..63
  int sks = (tid & 3) * 8;        // staging: k offset 0/8/16/24
  int srow = ridx[sar];

  for (int kc=0;kc<4;++kc) {
    __syncthreads();
    // stage A (64x32)
    {
      float* dst = &As[sar*36 + sks];
      if (srow < 0) {
        #pragma unroll
        for (int j=0;j<8;++j) dst[j]=0.f;
      } else if (xf) {
        const float4* s4 = reinterpret_cast<const float4*>((const float*)X + (long)srow*128 + kc*32 + sks);
        float4 v0 = s4[0], v1 = s4[1];
        *reinterpret_cast<float4*>(dst)   = v0;
        *reinterpret_cast<float4*>(dst+4) = v1;
      } else {
        const u16* s = (const u16*)X + (long)srow*128 + kc*32 + sks;
        #pragma unroll
        for (int j=0;j<8;++j) dst[j] = bf2f(s[j]);
      }
    }
    // stage W (contiguous 4096 f32 chunk), conflict-free linear
    #pragma unroll
    for (int j=0;j<4;++j) {
      float4 v = *reinterpret_cast<const float4*>(Wg + kc*4096 + j*1024 + tid*4);
      *reinterpret_cast<float4*>(&Ws[j*1024 + tid*4]) = v;
    }
    __syncthreads();
    // compute: 8 quads of 4 k
    #pragma unroll
    for (int kq=0;kq<8;++kq) {
      float wv[4][4];
      #pragma unroll
      for (int i=0;i<4;++i) {
        float4 wt = *reinterpret_cast<const float4*>(&Ws[(kq*4+i)*128 + cg*4]);
        wv[i][0]=wt.x; wv[i][1]=wt.y; wv[i][2]=wt.z; wv[i][3]=wt.w;
      }
      #pragma unroll
      for (int r=0;r<8;++r) {
        float4 a4 = *reinterpret_cast<const float4*>(&As[(rg_*8+r)*36 + kq*4]);
        float av[4] = {a4.x, a4.y, a4.z, a4.w};
        #pragma unroll
        for (int i=0;i<4;++i) {
          acc[r][0] += av[i]*wv[i][0];
          acc[r][1] += av[i]*wv[i][1];
          acc[r][2] += av[i]*wv[i][2];
          acc[r][3] += av[i]*wv[i][3];
        }
      }
    }
  }

  if (!dotmode) {
    const float* bp = bias ? (bias + (long)y*ybias + tblk*128 + cg*4) : nullptr;
    float b0=0,b1=0,b2=0,b3=0;
    if (bp){ b0=bp[0]; b1=bp[1]; b2=bp[2]; b3=bp[3]; }
    #pragma unroll
    for (int r=0;r<8;++r) {
      int rowg = ridx[rg_*8+r];
      if (rowg < 0) continue;
      float4 o;
      o.x=acc[r][0]+b0; o.y=acc[r][1]+b1; o.z=acc[r][2]+b2; o.w=acc[r][3]+b3;
      *reinterpret_cast<float4*>(out + (long)y*yostride + (long)rowg*128 + cg*4) = o;
    }
  } else {
    const float* ckp = ck + y*128 + cg*4;
    float c0=ckp[0], c1=ckp[1], c2=ckp[2], c3=ckp[3];
    #pragma unroll
    for (int r=0;r<8;++r) {
      int rowg = ridx[rg_*8+r];
      float d = 0.f;
      if (rowg >= 0) {
        const float* qp = qlin + (long)rowg*128 + cg*4;
        d = (acc[r][0]+c0)*qp[0] + (acc[r][1]+c1)*qp[1]
          + (acc[r][2]+c2)*qp[2] + (acc[r][3]+c3)*qp[3];
      }
      #pragma unroll
      for (int m=16;m;m>>=1) d += __shfl_xor(d, m, 64);   // reduce within 32-lane half
      if (cg==0 && rowg>=0) out[(long)rowg*4 + y] = 1.f/(1.f+expf(-d));
    }
  }
}

// ---------------------------------------------------------------------------
// qtr[n, h*32+d] = sum_m qn[n,h*32+m] * rel_att[r,h,d,m]  (via raT, coalesced)
__global__ __launch_bounds__(256) void qtr_kernel(
    const float* __restrict__ qn, const float* __restrict__ raT_r,
    float* __restrict__ qtr)
{
  int col = threadIdx.x & 127, rloc = threadIdx.x >> 7;
  int row = blockIdx.x*2 + rloc;
  int h = col >> 5, d = col & 31;
  const float* xr = qn + (long)row*128 + h*32;
  const float* rt = raT_r + h*1024;       // [m][d]
  float acc = 0.f;
  #pragma unroll 8
  for (int m=0;m<32;++m) acc += xr[m] * rt[m*32+d];
  qtr[(long)row*128 + col] = acc;
}

// per-relation edge pass: logit = dot32(kn[src,h], qtr[tgt,h]) * pri / sqrt(32)
__global__ __launch_bounds__(256) void epass_kernel(
    const float* __restrict__ kn, const float* __restrict__ qtr, const float* __restrict__ wcf,
    const int* __restrict__ ei, const int* __restrict__ et, int rsel,
    float* __restrict__ logits, unsigned* __restrict__ mxkey, int* __restrict__ deg)
{
  int gid = blockIdx.x*256 + threadIdx.x;   // E*H
  int e = gid >> 2, h = gid & 3;
  if (et[e] != rsel) return;
  int s = ei[e], t = ei[E_+e];
  const float4* ka = reinterpret_cast<const float4*>(kn + (long)s*128 + h*32);
  const float4* qa = reinterpret_cast<const float4*>(qtr + (long)t*128 + h*32);
  float acc = 0.f;
  #pragma unroll
  for (int i=0;i<8;++i) {
    float4 a = ka[i], b = qa[i];
    acc += a.x*b.x + a.y*b.y + a.z*b.z + a.w*b.w;
  }
  float lg = acc * wcf[W_PRI + rsel*H_+h] * 0.17677669529663687f;
  logits[gid] = lg;
  atomicMax(mxkey + t*H_+h, fmono(lg));
  if (h==0) atomicAdd(deg + t, 1);
}

__global__ __launch_bounds__(256) void eexp_kernel(
    const int* __restrict__ ei, float* __restrict__ logits,
    const unsigned* __restrict__ mxkey, float* __restrict__ sumex)
{
  int gid = blockIdx.x*256 + threadIdx.x;
  int e = gid >> 2, h = gid & 3;
  int t = ei[E_+e];
  float d = fminf(logits[gid] - monof(mxkey[t*H_+h]), 0.f);
  float ex = expf(d);
  logits[gid] = ex;
  atomicAdd(sumex + t*H_+h, ex);
}

// aggm2[k] = A_k @ WMk[k], A_k[n,j] = deg(n)·att[n,h]·vp[n,j]^(k+1) (k=2 cube-rooted)
__global__ __launch_bounds__(256) void aggk_kernel(
    const float* __restrict__ vn, const float* __restrict__ wcf,
    const int* __restrict__ ei, const int* __restrict__ et,
    const float* __restrict__ ex, const float* __restrict__ sumex, const int* __restrict__ deg,
    float* __restrict__ out0, float* __restrict__ out1, float* __restrict__ out2)
{
  __shared__ float As[2][128];
  int k = blockIdx.y;
  int col = threadIdx.x & 127, rloc = threadIdx.x >> 7;
  int n = blockIdx.x*2 + rloc;
  int h = col >> 5, m = col & 31;
  int s = ei[n], t = ei[E_+n], r = et[n];
  const float* vr = vn + (long)s*128 + h*32;
  const float* rm = wcf + W_RMSG + (r*H_+h)*1024;
  float vp = 0.f;
  #pragma unroll 8
  for (int d=0;d<32;++d) vp += vr[d]*rm[d*32+m];
  float att = ex[n*H_+h] / (sumex[t*H_+h] + 1e-16f);
  float sc  = (float)deg[n] * att;
  float a;
  if (k==0)      a = vp*sc;
  else if (k==1) a = vp*vp*sc;
  else { float a3 = vp*vp*vp*sc;
         a = (a3==0.f) ? 0.f : copysignf(cbrtf(fabsf(a3)+1e-18f), a3); }
  As[rloc][col] = a;
  __syncthreads();
  const float* Wk = wcf + W_WMK + k*16384;
  float acc = 0.f;
  #pragma unroll 8
  for (int i=0;i<128;++i) acc += As[rloc][i]*Wk[i*128+col];
  float* out = (k==0)?out0:(k==1)?out1:out2;
  out[(long)n*128 + col] = acc;
}

// gatemix: res = sum_k t_k·ag_k; h = gelu_exact(res)
__global__ __launch_bounds__(256) void gatemix_kernel(
    const float* __restrict__ tval,
    const float* __restrict__ ag0, const float* __restrict__ ag1, const float* __restrict__ ag2,
    float* __restrict__ hout)
{
  long gid = (long)blockIdx.x*256 + threadIdx.x;   // N*128
  int n = (int)(gid >> 7);
  float res = tval[n*4+0]*ag0[gid] + tval[n*4+1]*ag1[gid] + tval[n*4+2]*ag2[gid];
  hout[gid] = 0.5f*res*(1.f+erff(res*0.70710678118654752f));
}

__global__ __launch_bounds__(256) void lnf_kernel(
    const float* __restrict__ trans, const void* __restrict__ x, const int* __restrict__ flags,
    const int* __restrict__ nt, const float* __restrict__ wcf, void* __restrict__ outv)
{
  int wave = threadIdx.x >> 6, lane = threadIdx.x & 63;
  int n = blockIdx.x*4 + wave;
  int j = lane*2;
  int xf = flags[0];
  int t = nt[n];
  float alpha = 1.f/(1.f+expf(-wcf[W_SKIP+t]));
  long base = (long)n*128 + j;
  float y0 = alpha*trans[base]   + (1.f-alpha)*ldx(x, base,   xf);
  float y1 = alpha*trans[base+1] + (1.f-alpha)*ldx(x, base+1, xf);
  float mu = wredsum(y0+y1) * (1.f/128.f);
  float d0 = y0-mu, d1 = y1-mu;
  float var = wredsum(d0*d0+d1*d1) * (1.f/128.f);
  float inv = rsqrtf(var + 1e-5f);
  float o0 = d0*inv*wcf[W_LNG + t*128+j]   + wcf[W_LNB + t*128+j];
  float o1 = d1*inv*wcf[W_LNG + t*128+j+1] + wcf[W_LNB + t*128+j+1];
  if (xf) {
    ((float*)outv)[base]   = o0;
    ((float*)outv)[base+1] = o1;
  } else {
    unsigned o = (unsigned)f2bf(o0) | ((unsigned)f2bf(o1)<<16);
    *reinterpret_cast<unsigned*>(((u16*)outv)+base) = o;
  }
}

// ---------------------------------------------------------------------------
extern "C" void kernel_launch(void* const* d_in, const int* in_sizes, int n_in,
                              void* d_out, int out_size, void* d_ws, size_t ws_size,
                              hipStream_t stream) {
  char* w = (char*)d_ws;
  int*      flags = (int*)     (w + OFF_FLAGS);
  float*    wcf   = (float*)   (w + OFF_WCF);
  int*      nt32  = (int*)     (w + OFF_NT32);
  int*      ei32  = (int*)     (w + OFF_EI32);
  int*      et32  = (int*)     (w + OFF_ET32);
  int*      perm  = (int*)     (w + OFF_PERM);
  int*      pcnt  = (int*)     (w + OFF_PCNT);
  float*    raT   = (float*)   (w + OFF_TVAL);   // raT then tval (disjoint lifetimes)
  float*    tval  = (float*)   (w + OFF_TVAL);
  float*    logits= (float*)   (w + OFF_LOG);
  unsigned* mxkey = (unsigned*)(w + OFF_LOG + 5120000);
  float*    sumex = (float*)   (w + OFF_LOG + 5760000);
  int*      deg   = (int*)     (w + OFF_LOG + 6400000);
  float*    MT    = (float*)   (w + OFF_LOG);            // overlays dead logits after aggk
  float*    ckb   = (float*)   (w + OFF_LOG + 786432);   // 196608 f32 * 4B
  float*    qn    = (float*)   (w + OFF_QN);
  float*    ag0   = (float*)   (w + OFF_QN);
  float*    trans = (float*)   (w + OFF_QN);
  float*    kn    = (float*)   (w + OFF_KN);
  float*    ag1   = (float*)   (w + OFF_KN);
  float*    vn    = (float*)   (w + OFF_VN);
  float*    qlin  = (float*)   (w + OFF_QLIN);
  float*    hbuf  = (float*)   (w + OFF_QLIN);
  float*    qtrb  = (float*)   (w + OFF_QTR);
  float*    ag2   = (float*)   (w + OFF_QTR);

  // s0: dtype detect + canonicalize
  detect_kernel<<<1,256,0,stream>>>((const u16*)d_in[0], (const int*)d_in[1], flags);
  FPtrs fp;
  fp.p[0]=d_in[5];  fp.p[1]=d_in[7];  fp.p[2]=d_in[9];  fp.p[3]=d_in[11];
  fp.p[4]=d_in[6];  fp.p[5]=d_in[8];  fp.p[6]=d_in[10]; fp.p[7]=d_in[12];
  fp.p[8]=d_in[13]; fp.p[9]=d_in[14]; fp.p[10]=d_in[15];fp.p[11]=d_in[16];
  fp.p[12]=d_in[17];fp.p[13]=d_in[18];fp.p[14]=d_in[19];fp.p[15]=d_in[20];
  fp.p[16]=d_in[21];fp.p[17]=d_in[22];fp.p[18]=d_in[23];fp.p[19]=d_in[24];
  convf_kernel<<<1451,256,0,stream>>>(flags, fp, wcf);
  idxconv_kernel<<<3907,256,0,stream>>>(flags, (const int*)d_in[1],
                                        (const int*)d_in[2], (const int*)d_in[3],
                                        nt32, ei32, et32);
  // s0.7: type-sorted row permutation
  pinit_kernel <<<157,256,0,stream>>>(perm, pcnt);
  pcount_kernel<<<157,256,0,stream>>>(nt32, pcnt);
  pofs_kernel  <<<1,64,0,stream>>>(pcnt);
  pscat_kernel <<<157,256,0,stream>>>(nt32, pcnt, perm);
  // s1: raT
  prepA_kernel<<<80,256,0,stream>>>(wcf, raT);

  // s2: q/k/v typed projections in ONE batched dispatch (grid.y = 3)
  P3 xin; xin.a[0]=(const float*)d_in[0]; xin.a[1]=xin.a[0]; xin.a[2]=xin.a[0];
  gemmt_kernel<<<dim3(628,3),256,0,stream>>>(xin, flags, 0,
      wcf+W_QW, 49152, wcf+W_QB, 384, perm, nt32, 0, nullptr, nullptr,
      qn, 5120000);
  // s3: qlin (untyped)
  gemmt_kernel<<<dim3(625,1),256,0,stream>>>(xin, flags, 0,
      wcf+W_WQ, 0, wcf+W_BQ, 0, nullptr, nullptr, 0, nullptr, nullptr,
      qlin, 0);

  // s5.5: init softmax accumulators
  init_kernel<<<625,256,0,stream>>>(mxkey, sumex, deg);

  // s6: per-relation qtr + edge pass
  for (int r=0; r<R_; ++r) {
    qtr_kernel<<<20000,256,0,stream>>>(qn, raT + r*4096, qtrb);
    epass_kernel<<<5000,256,0,stream>>>(kn, qtrb, wcf, ei32, et32, r, logits, mxkey, deg);
  }
  // s7: exp + segment-sum
  eexp_kernel<<<5000,256,0,stream>>>(ei32, logits, mxkey, sumex);

  // s8: aggm2[k] (vp on the fly)
  aggk_kernel<<<dim3(20000,3),256,0,stream>>>(vn, wcf, ei32, et32, logits, sumex, deg,
                                              ag0, ag1, ag2);

  // s8.5: MT/ck into dead logits region
  prepB_kernel<<<dim3(128,3),128,0,stream>>>(wcf, MT, ckb);

  // s9: gate scalars: tval[n,k] = sigmoid(qlin·(ag_k@MT_k + ck_k))  (dot-mode gemmt)
  P3 xag; xag.a[0]=ag0; xag.a[1]=ag1; xag.a[2]=ag2;
  gemmt_kernel<<<dim3(625,3),256,0,stream>>>(xag, flags, 1,
      MT, 16384, nullptr, 0, nullptr, nullptr, 1, qlin, ckb,
      tval, 0);

  // s10: mix + gelu -> hbuf (overlays qlin; qlin dead after dot-mode)
  gatemix_kernel<<<20000,256,0,stream>>>(tval, ag0, ag1, ag2, hbuf);

  // s11: trans = typed(h, a_w, a_b)
  P3 xh; xh.a[0]=hbuf; xh.a[1]=hbuf; xh.a[2]=hbuf;
  gemmt_kernel<<<dim3(628,1),256,0,stream>>>(xh, flags, 1,
      wcf+W_AW, 0, wcf+W_AB, 0, perm, nt32, 0, nullptr, nullptr,
      trans, 0);

  // s12: skip-mix + per-type LayerNorm -> out
  lnf_kernel<<<10000,256,0,stream>>>(trans, d_in[0], flags, nt32, wcf, d_out);

  (void)in_sizes; (void)n_in; (void)out_size; (void)ws_size;
}